// Round 1
// baseline (618.819 us; speedup 1.0000x reference)
//
#include <hip/hip_runtime.h>
#include <hip/hip_bf16.h>

// TopKRouter: logits = x[16384,4096] @ W[64,4096]^T; softmax; top-2; z_loss.
// Strategy: exact 3-way bf16 split GEMM (6 MFMA products == fp32 accuracy),
// no LDS (W pre-split into B-fragment order in d_ws, x split in registers),
// K split 4-way for occupancy (2048 single-wave blocks = 8 waves/CU).

typedef __bf16  bf16x8  __attribute__((ext_vector_type(8)));
typedef float   f32x16  __attribute__((ext_vector_type(16)));

#define BS_TOK 16384           // B*S tokens
#define H_DIM  4096
#define E_DIM  64
#define KSPLIT 4
#define KCHUNK (H_DIM / KSPLIT)   // 1024
#define KSTEPS (KCHUNK / 16)      // 64 k-steps of K=16 per chunk
#define WS_LOGITS_OFF (2u << 20)  // logits partials at +2 MiB in d_ws

__device__ __forceinline__ void split3(float v, __bf16 &b0, __bf16 &b1, __bf16 &b2) {
    b0 = (__bf16)v;            // top 8 mantissa bits (RN)
    float r = v - (float)b0;   // exact in fp32
    b1 = (__bf16)r;            // next 8 bits
    float r2 = r - (float)b1;  // exact; <=8 significant bits remain
    b2 = (__bf16)r2;           // exact: v == b0+b1+b2
}

// Kernel 0: split gate_w into 3 bf16 terms, stored in 32x32x16 MFMA
// B-fragment order. frag f = (kb*2 + nt)*3 + term; element [f*64 + lane].
// lane holds W_term[n = nt*32 + (lane&31)][k = kb*16 + (lane>>5)*8 + j], j=0..7
__global__ void prep_w(const float* __restrict__ gw, bf16x8* __restrict__ wb) {
    int idx  = blockIdx.x * blockDim.x + threadIdx.x;   // 0..32767
    int kb   = idx >> 7;           // 0..255
    int rem  = idx & 127;
    int nt   = rem >> 6;           // 0..1
    int lane = rem & 63;
    int n  = nt * 32 + (lane & 31);
    int kk = kb * 16 + ((lane >> 5) << 3);
    const float* p = gw + (size_t)n * H_DIM + kk;
    bf16x8 t0, t1, t2;
#pragma unroll
    for (int j = 0; j < 8; ++j) {
        __bf16 a, b, c;
        split3(p[j], a, b, c);
        t0[j] = a; t1[j] = b; t2[j] = c;
    }
    size_t fb = (size_t)(kb * 2 + nt) * 3;
    wb[(fb + 0) * 64 + lane] = t0;
    wb[(fb + 1) * 64 + lane] = t1;
    wb[(fb + 2) * 64 + lane] = t2;
}

// Kernel 1: one wave per (32-token tile, K-chunk). Wave tile M32 x N64.
// A-frag: lane holds x[m0 + (lane&31)][k0 + (lane>>5)*8 + j] split into 3 terms.
// 6 term-products accumulated: a0w0+a1w0+a2w0+a0w1+a1w1+a0w2.
__global__ __launch_bounds__(64, 2) void gemm_split(
        const float* __restrict__ x, const bf16x8* __restrict__ wb,
        float* __restrict__ lg) {
    int bid  = blockIdx.x;
    int mt   = bid >> 2;          // 0..511
    int kc   = bid & 3;           // K-chunk
    int lane = threadIdx.x;       // 0..63
    int half = lane >> 5;
    int m0   = mt * 32;
    int row  = m0 + (lane & 31);
    const float* xp = x + (size_t)row * H_DIM + kc * KCHUNK + half * 8;
    int kb0 = kc * KSTEPS;        // absolute first k-block of this chunk
    const bf16x8* wb_base = wb + (size_t)kb0 * 6 * 64 + lane;

    f32x16 acc0, acc1;
#pragma unroll
    for (int r = 0; r < 16; ++r) { acc0[r] = 0.f; acc1[r] = 0.f; }

    // software pipeline: prefetch next step's x + W frags
    float4 cx0 = *(const float4*)(xp);
    float4 cx1 = *(const float4*)(xp + 4);
    bf16x8 cb0 = wb_base[0*64], cb1 = wb_base[1*64], cb2 = wb_base[2*64];
    bf16x8 cb3 = wb_base[3*64], cb4 = wb_base[4*64], cb5 = wb_base[5*64];

    for (int ks = 0; ks < KSTEPS; ++ks) {
        int ksn = (ks < KSTEPS - 1) ? ks + 1 : ks;   // clamped (last iter redundant)
        float4 nx0 = *(const float4*)(xp + ksn * 16);
        float4 nx1 = *(const float4*)(xp + ksn * 16 + 4);
        const bf16x8* wn = wb_base + (size_t)ksn * 6 * 64;
        bf16x8 nb0 = wn[0*64], nb1 = wn[1*64], nb2 = wn[2*64];
        bf16x8 nb3 = wn[3*64], nb4 = wn[4*64], nb5 = wn[5*64];

        bf16x8 a0, a1, a2;
        float xs[8] = {cx0.x, cx0.y, cx0.z, cx0.w, cx1.x, cx1.y, cx1.z, cx1.w};
#pragma unroll
        for (int j = 0; j < 8; ++j) {
            __bf16 h0, h1, h2;
            split3(xs[j], h0, h1, h2);
            a0[j] = h0; a1[j] = h1; a2[j] = h2;
        }
        // N-tile 0 (experts 0..31)
        acc0 = __builtin_amdgcn_mfma_f32_32x32x16_bf16(a0, cb0, acc0, 0, 0, 0);
        acc0 = __builtin_amdgcn_mfma_f32_32x32x16_bf16(a1, cb0, acc0, 0, 0, 0);
        acc0 = __builtin_amdgcn_mfma_f32_32x32x16_bf16(a2, cb0, acc0, 0, 0, 0);
        acc0 = __builtin_amdgcn_mfma_f32_32x32x16_bf16(a0, cb1, acc0, 0, 0, 0);
        acc0 = __builtin_amdgcn_mfma_f32_32x32x16_bf16(a1, cb1, acc0, 0, 0, 0);
        acc0 = __builtin_amdgcn_mfma_f32_32x32x16_bf16(a0, cb2, acc0, 0, 0, 0);
        // N-tile 1 (experts 32..63)
        acc1 = __builtin_amdgcn_mfma_f32_32x32x16_bf16(a0, cb3, acc1, 0, 0, 0);
        acc1 = __builtin_amdgcn_mfma_f32_32x32x16_bf16(a1, cb3, acc1, 0, 0, 0);
        acc1 = __builtin_amdgcn_mfma_f32_32x32x16_bf16(a2, cb3, acc1, 0, 0, 0);
        acc1 = __builtin_amdgcn_mfma_f32_32x32x16_bf16(a0, cb4, acc1, 0, 0, 0);
        acc1 = __builtin_amdgcn_mfma_f32_32x32x16_bf16(a1, cb4, acc1, 0, 0, 0);
        acc1 = __builtin_amdgcn_mfma_f32_32x32x16_bf16(a0, cb5, acc1, 0, 0, 0);

        cx0 = nx0; cx1 = nx1;
        cb0 = nb0; cb1 = nb1; cb2 = nb2; cb3 = nb3; cb4 = nb4; cb5 = nb5;
    }

    // C/D layout (m74/m101): col = lane&31, row = (reg&3) + 8*(reg>>2) + 4*(lane>>5)
    size_t obase = (size_t)kc * BS_TOK * E_DIM;
    int col = lane & 31;
#pragma unroll
    for (int r = 0; r < 16; ++r) {
        int mm = m0 + (r & 3) + ((r >> 2) << 3) + (half << 2);
        lg[obase + (size_t)mm * E_DIM + col]      = acc0[r];
        lg[obase + (size_t)mm * E_DIM + 32 + col] = acc1[r];
    }
}

// Kernel 2: one wave per token. lane <-> expert. Sum K-partials, z-loss,
// softmax, top-2 with lower-index tie-break (matches stable top_k).
__global__ __launch_bounds__(256) void epilogue(const float* __restrict__ lg,
                                                float* __restrict__ out) {
    int lane = threadIdx.x & 63;
    int t    = blockIdx.x * 4 + (threadIdx.x >> 6);   // token id

    float l = 0.f;
#pragma unroll
    for (int s = 0; s < KSPLIT; ++s)
        l += lg[((size_t)s * BS_TOK + t) * E_DIM + lane];

    // z_loss = mean(logits^2)
    float z = l * l;
#pragma unroll
    for (int off = 32; off; off >>= 1) z += __shfl_xor(z, off);
    if (lane == 0)
        atomicAdd(out + 4 * BS_TOK + 1, z * (1.0f / (float)(BS_TOK * E_DIM)));

    // softmax over 64 experts
    float m = l;
#pragma unroll
    for (int off = 32; off; off >>= 1) m = fmaxf(m, __shfl_xor(m, off));
    float e = expf(l - m);
    float d = e;
#pragma unroll
    for (int off = 32; off; off >>= 1) d += __shfl_xor(d, off);
    float sc = e / d;

    // top-1 (argmax with min-index tie-break)
    float s1 = sc; int i1 = lane;
#pragma unroll
    for (int off = 32; off; off >>= 1) {
        float os = __shfl_xor(s1, off); int oi = __shfl_xor(i1, off);
        if (os > s1 || (os == s1 && oi < i1)) { s1 = os; i1 = oi; }
    }
    // top-2: mask out winner (scores >= 0, so -1 works as -inf)
    float sm = (lane == i1) ? -1.0f : sc;
    float s2 = sm; int i2 = lane;
#pragma unroll
    for (int off = 32; off; off >>= 1) {
        float os = __shfl_xor(s2, off); int oi = __shfl_xor(i2, off);
        if (os > s2 || (os == s2 && oi < i2)) { s2 = os; i2 = oi; }
    }

    if (lane == 0) {
        out[2 * t]                  = (float)i1;   // topk_idx as float
        out[2 * t + 1]              = (float)i2;
        out[2 * BS_TOK + 2 * t]     = s1;          // topk_scores
        out[2 * BS_TOK + 2 * t + 1] = s2;
    }
}

extern "C" void kernel_launch(void* const* d_in, const int* in_sizes, int n_in,
                              void* d_out, int out_size, void* d_ws, size_t ws_size,
                              hipStream_t stream) {
    const float* x  = (const float*)d_in[0];   // [4,4096,4096] f32
    const float* gw = (const float*)d_in[1];   // [64,4096] f32
    float* out = (float*)d_out;                // idx(32768) | scores(32768) | aux | z
    bf16x8* wb = (bf16x8*)d_ws;                // 1.5 MiB pre-split W frags
    float*  lg = (float*)((char*)d_ws + WS_LOGITS_OFF);  // 4 x 4 MiB partials

    // aux_loss = 0 exactly; z_loss accumulator zeroed for atomics
    hipMemsetAsync((char*)d_out + (size_t)(4 * BS_TOK) * sizeof(float), 0,
                   2 * sizeof(float), stream);
    prep_w<<<128, 256, 0, stream>>>(gw, wb);
    gemm_split<<<(BS_TOK / 32) * KSPLIT, 64, 0, stream>>>(x, wb, lg);
    epilogue<<<BS_TOK / 4, 256, 0, stream>>>(lg, out);
}

// Round 2
// 397.718 us; speedup vs baseline: 1.5559x; 1.5559x over previous
//
#include <hip/hip_runtime.h>
#include <hip/hip_bf16.h>

// TopKRouter: logits = x[16384,4096] @ W[64,4096]^T; softmax; top-2; z_loss.
// v2: exact 3-way bf16 split GEMM (6 MFMA products == fp32 accuracy).
//  - gemm: 256-thr blocks, M64 tile, x staged to LDS via global_load_lds(16B),
//    XOR-swizzled chunks (conflict-floor ds_read_b128), dbuf panels,
//    4 waves = 2 row-halves x 2 K-halves (intra-block LDS reduce).
//  - epilogue: per-block z partial to d_ws + zreduce kernel (round-1's 210us
//    was 16384 same-address atomicAdds serializing).

typedef __bf16  bf16x8  __attribute__((ext_vector_type(8)));
typedef float   f32x16  __attribute__((ext_vector_type(16)));

#define BS_TOK 16384              // B*S tokens
#define H_DIM  4096
#define E_DIM  64
#define KSPLIT 4
#define KCHUNK (H_DIM / KSPLIT)   // 1024
#define NPANEL (KCHUNK / 64)      // 16 panels of 64 floats
#define WS_ZBUF_OFF (1536u << 10) // z partials at +1.5 MiB
#define WS_LG_OFF   (2u << 20)    // logits partials at +2 MiB (4 x 4 MiB)

__device__ __forceinline__ void split3(float v, __bf16 &b0, __bf16 &b1, __bf16 &b2) {
    b0 = (__bf16)v;            // top 8 mantissa bits (RN)
    float r = v - (float)b0;   // exact in fp32
    b1 = (__bf16)r;            // next 8 bits
    float r2 = r - (float)b1;  // exact
    b2 = (__bf16)r2;           // v == b0+b1+b2 (within fp32)
}

__device__ __forceinline__ void async_copy16(const float* gp, float* lp) {
    __builtin_amdgcn_global_load_lds(
        (const __attribute__((address_space(1))) void*)gp,
        (__attribute__((address_space(3))) void*)lp, 16, 0, 0);
}

// Kernel 0: split gate_w into 3 bf16 terms in 32x32x16 MFMA B-frag order.
// frag f = (kb*2 + nt)*3 + term = kb*6 + nt*3 + term; element [f*64 + lane].
// lane holds W_term[n = nt*32 + (lane&31)][k = kb*16 + (lane>>5)*8 + j]
__global__ void prep_w(const float* __restrict__ gw, bf16x8* __restrict__ wb) {
    int idx  = blockIdx.x * blockDim.x + threadIdx.x;   // 0..32767
    int kb   = idx >> 7;
    int rem  = idx & 127;
    int nt   = rem >> 6;
    int lane = rem & 63;
    int n  = nt * 32 + (lane & 31);
    int kk = kb * 16 + ((lane >> 5) << 3);
    const float* p = gw + (size_t)n * H_DIM + kk;
    bf16x8 t0, t1, t2;
#pragma unroll
    for (int j = 0; j < 8; ++j) {
        __bf16 a, b, c;
        split3(p[j], a, b, c);
        t0[j] = a; t1[j] = b; t2[j] = c;
    }
    size_t fb = (size_t)(kb * 2 + nt) * 3;
    wb[(fb + 0) * 64 + lane] = t0;
    wb[(fb + 1) * 64 + lane] = t1;
    wb[(fb + 2) * 64 + lane] = t2;
}

// Kernel 1: block = 256 thr (4 waves), tile M64 x N64 x KCHUNK.
// Wave w: rows (w&1)*32..+32, K-half (w>>1) of each 64-float panel.
// Panels staged to LDS dbuf via global_load_lds; chunk c of row g stored at
// slot c ^ (g&15) (swizzle applied on the GLOBAL side; LDS dest is forced
// to base + lane*16).
__global__ __launch_bounds__(256, 4) void gemm_split(
        const float* __restrict__ x, const bf16x8* __restrict__ wb,
        float* __restrict__ lg) {
    __shared__ float lds[2 * 4096];   // 2 x 16 KiB panels

    int bid = blockIdx.x;
    int mt  = bid >> 2;               // 0..255 (M64 tiles)
    int kc  = bid & 3;                // K-chunk
    int tid = threadIdx.x;
    int w   = tid >> 6;               // wave 0..3
    int l   = tid & 63;
    int m0  = mt * 64;
    int rw  = (w & 1) * 32;           // wave's row base in tile
    int kh  = w >> 1;                 // wave's K-half of panel

    // --- staging addressing (4 rounds of 16B per thread per panel) ---
    const float* gpan[4];
    int ldso[4];
    int s_slot = l & 15;
#pragma unroll
    for (int r = 0; r < 4; ++r) {
        int g = r * 16 + w * 4 + (l >> 4);          // row in tile 0..63
        int c = s_slot ^ (g & 15);                  // swizzled global chunk
        gpan[r] = x + (size_t)(m0 + g) * H_DIM + kc * KCHUNK + c * 4;
        ldso[r] = (r * 16 + w * 4) * 64;            // wave-uniform float offset
    }

    f32x16 acc0, acc1;
#pragma unroll
    for (int r = 0; r < 16; ++r) { acc0[r] = 0.f; acc1[r] = 0.f; }

    // prologue: stage panel 0 into buf 0
#pragma unroll
    for (int r = 0; r < 4; ++r) async_copy16(gpan[r], &lds[ldso[r]]);

    int row  = rw + (l & 31);
    int half = l >> 5;
    int rsw  = row & 15;

    for (int p = 0; p < NPANEL; ++p) {
        __syncthreads();   // drains own vmcnt -> panel p ready; prev compute done
        if (p + 1 < NPANEL) {
            int b = (p + 1) & 1;
#pragma unroll
            for (int r = 0; r < 4; ++r)
                async_copy16(gpan[r] + (p + 1) * 64, &lds[b * 4096 + ldso[r]]);
        }
        int bufo = (p & 1) * 4096;
#pragma unroll
        for (int ks2 = 0; ks2 < 2; ++ks2) {
            int ks     = kh * 2 + ks2;              // k-step in panel 0..3
            int ks_abs = kc * 64 + p * 4 + ks;      // absolute k-block 0..255
            int c0     = ks * 4 + half * 2;
            float4 xa = *(const float4*)&lds[bufo + row * 64 + ((c0 ^ rsw) << 2)];
            float4 xb = *(const float4*)&lds[bufo + row * 64 + (((c0 + 1) ^ rsw) << 2)];
            bf16x8 a0, a1, a2;
            float xs[8] = {xa.x, xa.y, xa.z, xa.w, xb.x, xb.y, xb.z, xb.w};
#pragma unroll
            for (int j = 0; j < 8; ++j) {
                __bf16 h0, h1, h2;
                split3(xs[j], h0, h1, h2);
                a0[j] = h0; a1[j] = h1; a2[j] = h2;
            }
            const bf16x8* wp = wb + (size_t)ks_abs * 6 * 64 + l;
            bf16x8 b0 = wp[0*64], b1 = wp[1*64], b2 = wp[2*64];
            bf16x8 b3 = wp[3*64], b4 = wp[4*64], b5 = wp[5*64];
            // experts 0..31
            acc0 = __builtin_amdgcn_mfma_f32_32x32x16_bf16(a0, b0, acc0, 0, 0, 0);
            acc0 = __builtin_amdgcn_mfma_f32_32x32x16_bf16(a1, b0, acc0, 0, 0, 0);
            acc0 = __builtin_amdgcn_mfma_f32_32x32x16_bf16(a2, b0, acc0, 0, 0, 0);
            acc0 = __builtin_amdgcn_mfma_f32_32x32x16_bf16(a0, b1, acc0, 0, 0, 0);
            acc0 = __builtin_amdgcn_mfma_f32_32x32x16_bf16(a1, b1, acc0, 0, 0, 0);
            acc0 = __builtin_amdgcn_mfma_f32_32x32x16_bf16(a0, b2, acc0, 0, 0, 0);
            // experts 32..63
            acc1 = __builtin_amdgcn_mfma_f32_32x32x16_bf16(a0, b3, acc1, 0, 0, 0);
            acc1 = __builtin_amdgcn_mfma_f32_32x32x16_bf16(a1, b3, acc1, 0, 0, 0);
            acc1 = __builtin_amdgcn_mfma_f32_32x32x16_bf16(a2, b3, acc1, 0, 0, 0);
            acc1 = __builtin_amdgcn_mfma_f32_32x32x16_bf16(a0, b4, acc1, 0, 0, 0);
            acc1 = __builtin_amdgcn_mfma_f32_32x32x16_bf16(a1, b4, acc1, 0, 0, 0);
            acc1 = __builtin_amdgcn_mfma_f32_32x32x16_bf16(a0, b5, acc1, 0, 0, 0);
        }
    }

    // --- intra-block K-half reduction via LDS (reuse buf area) ---
    // C/D layout: col = lane&31, row = (reg&3) + 8*(reg>>2) + 4*(lane>>5)
    int col = l & 31;
    if (kh == 1) {   // waves 2,3 deposit their half
#pragma unroll
        for (int r = 0; r < 16; ++r) {
            int mm = rw + (r & 3) + ((r >> 2) << 3) + (half << 2);
            lds[mm * 64 + col]      = acc0[r];
            lds[mm * 64 + 32 + col] = acc1[r];
        }
    }
    __syncthreads();
    if (kh == 0) {   // waves 0,1 add and write the K-chunk partial
        size_t obase = (size_t)kc * BS_TOK * E_DIM + (size_t)m0 * E_DIM;
#pragma unroll
        for (int r = 0; r < 16; ++r) {
            int mm = rw + (r & 3) + ((r >> 2) << 3) + (half << 2);
            lg[obase + (size_t)mm * E_DIM + col]
                = acc0[r] + lds[mm * 64 + col];
            lg[obase + (size_t)mm * E_DIM + 32 + col]
                = acc1[r] + lds[mm * 64 + 32 + col];
        }
    }
}

// Kernel 2: one wave per token. Sum K-partials, softmax, top-2 (low-index
// tie-break), z partial per block (NO same-address atomics).
__global__ __launch_bounds__(256) void epilogue(const float* __restrict__ lg,
                                                float* __restrict__ out,
                                                float* __restrict__ zbuf) {
    __shared__ float zsh[4];
    int lane = threadIdx.x & 63;
    int w    = threadIdx.x >> 6;
    int t    = blockIdx.x * 4 + w;

    float l = 0.f;
#pragma unroll
    for (int s = 0; s < KSPLIT; ++s)
        l += lg[((size_t)s * BS_TOK + t) * E_DIM + lane];

    float z = l * l;
#pragma unroll
    for (int off = 32; off; off >>= 1) z += __shfl_xor(z, off);
    if (lane == 0) zsh[w] = z;

    float m = l;
#pragma unroll
    for (int off = 32; off; off >>= 1) m = fmaxf(m, __shfl_xor(m, off));
    float e = expf(l - m);
    float d = e;
#pragma unroll
    for (int off = 32; off; off >>= 1) d += __shfl_xor(d, off);
    float sc = e / d;

    float s1 = sc; int i1 = lane;
#pragma unroll
    for (int off = 32; off; off >>= 1) {
        float os = __shfl_xor(s1, off); int oi = __shfl_xor(i1, off);
        if (os > s1 || (os == s1 && oi < i1)) { s1 = os; i1 = oi; }
    }
    float sm = (lane == i1) ? -1.0f : sc;
    float s2 = sm; int i2 = lane;
#pragma unroll
    for (int off = 32; off; off >>= 1) {
        float os = __shfl_xor(s2, off); int oi = __shfl_xor(i2, off);
        if (os > s2 || (os == s2 && oi < i2)) { s2 = os; i2 = oi; }
    }

    if (lane == 0) {
        out[2 * t]                  = (float)i1;
        out[2 * t + 1]              = (float)i2;
        out[2 * BS_TOK + 2 * t]     = s1;
        out[2 * BS_TOK + 2 * t + 1] = s2;
    }
    __syncthreads();
    if (threadIdx.x == 0)
        zbuf[blockIdx.x] = zsh[0] + zsh[1] + zsh[2] + zsh[3];
}

// Kernel 3: reduce 4096 z partials -> aux_loss (=0) and z_loss.
__global__ __launch_bounds__(256) void zreduce(const float* __restrict__ zbuf,
                                               float* __restrict__ out) {
    __shared__ float sh[4];
    int tid = threadIdx.x;
    float s = 0.f;
#pragma unroll
    for (int i = 0; i < 16; ++i) s += zbuf[tid + 256 * i];
#pragma unroll
    for (int off = 32; off; off >>= 1) s += __shfl_xor(s, off);
    if ((tid & 63) == 0) sh[tid >> 6] = s;
    __syncthreads();
    if (tid == 0) {
        out[4 * BS_TOK]     = 0.0f;  // aux_loss
        out[4 * BS_TOK + 1] = (sh[0] + sh[1] + sh[2] + sh[3])
                              * (1.0f / (float)(BS_TOK * E_DIM));
    }
}

extern "C" void kernel_launch(void* const* d_in, const int* in_sizes, int n_in,
                              void* d_out, int out_size, void* d_ws, size_t ws_size,
                              hipStream_t stream) {
    const float* x  = (const float*)d_in[0];   // [4,4096,4096] f32
    const float* gw = (const float*)d_in[1];   // [64,4096] f32
    float* out  = (float*)d_out;               // idx | scores | aux | z
    bf16x8* wb  = (bf16x8*)d_ws;                           // 1.5 MiB W frags
    float*  zbf = (float*)((char*)d_ws + WS_ZBUF_OFF);     // 16 KiB z partials
    float*  lg  = (float*)((char*)d_ws + WS_LG_OFF);       // 16 MiB logit partials

    prep_w<<<128, 256, 0, stream>>>(gw, wb);
    gemm_split<<<(BS_TOK / 64) * KSPLIT, 256, 0, stream>>>(x, wb, lg);
    epilogue<<<BS_TOK / 4, 256, 0, stream>>>(lg, out, zbf);
    zreduce<<<1, 256, 0, stream>>>(zbf, out);
}